// Round 1
// baseline (157.046 us; speedup 1.0000x reference)
//
#include <hip/hip_runtime.h>
#include <stdint.h>
#include <stddef.h>

typedef __attribute__((ext_vector_type(8))) short short8;
typedef __attribute__((ext_vector_type(4))) float f32x4;

__device__ __forceinline__ unsigned short f2bf(float f) {
    union { float f; uint32_t u; } v;
    v.f = f;
    uint32_t u = v.u;
    u += 0x7FFFu + ((u >> 16) & 1u);
    return (unsigned short)(u >> 16);
}

// ---------------- weight prep: transpose fp32 [R][C] -> bf16 [C][R] ----------------
__global__ __launch_bounds__(1024) void transpose_to_bf16(
    const float* __restrict__ src, unsigned short* __restrict__ dst, int R, int C)
{
    __shared__ float tile[32][33];
    const int c0 = blockIdx.x * 32, r0 = blockIdx.y * 32;
    const int tx = threadIdx.x, ty = threadIdx.y;
    tile[ty][tx] = src[(size_t)(r0 + ty) * C + (c0 + tx)];
    __syncthreads();
    dst[(size_t)(c0 + ty) * R + (r0 + tx)] = f2bf(tile[tx][ty]);
}

// ---------------- structural features + pack x = [feat | s] as bf16 ----------------
// Grid: 38400 blocks (m = t*19200 + n*4800 + l), 128 threads (one per anchor a).
__global__ __launch_bounds__(128) void struct_pack(
    const float* __restrict__ feat0, const float* __restrict__ feat1,
    const float* __restrict__ pts0,  const float* __restrict__ pts1,
    const int* __restrict__ ids0,    const int* __restrict__ ids1,
    unsigned short* __restrict__ xw)
{
    const int m = blockIdx.x;
    const int t = m / 19200;
    const int r = m % 19200;
    const int n = r / 4800;
    const int l = r % 4800;
    const float* feat = t ? feat1 : feat0;
    const float* pts  = (t ? pts1 : pts0) + (size_t)n * (307200 * 3);
    const int*   ids  = (t ? ids1 : ids0) + n * 128;
    const int a = threadIdx.x;

    const int lr = l / 80, lc = l % 80;
    const int p  = (lr * 8) * 640 + lc * 8;
    const float cx = pts[p * 3 + 0], cy = pts[p * 3 + 1], cz = pts[p * 3 + 2];

    const int id = ids[a];
    const float ax = pts[id * 3 + 0], ay = pts[id * 3 + 1], az = pts[id * 3 + 2];
    const float dx = cx - ax, dy = cy - ay, dz = cz - az;
    const float dist = dx * dx + dy * dy + dz * dz;

    __shared__ float red[4][128];
    red[0][a] = fabsf(dx);
    red[1][a] = fabsf(dy);
    red[2][a] = fabsf(dz);
    red[3][a] = dist;            // dist >= 0, |dist| == dist
    __syncthreads();
    for (int off = 64; off > 0; off >>= 1) {
        if (a < off) {
            red[0][a] += red[0][a + off];
            red[1][a] += red[1][a + off];
            red[2][a] += red[2][a + off];
            red[3][a] += red[3][a + off];
        }
        __syncthreads();
    }
    const float i0 = 1.0f / red[0][0];
    const float i1 = 1.0f / red[1][0];
    const float i2 = 1.0f / red[2][0];
    const float i3 = 1.0f / red[3][0];

    unsigned short* xrow = xw + (size_t)m * 768;
    const float* frow = feat + (size_t)(n * 4800 + l) * 256;
    xrow[a]        = f2bf(frow[a]);
    xrow[a + 128]  = f2bf(frow[a + 128]);
    xrow[256 + 0 * 128 + a] = f2bf(dx * i0);
    xrow[256 + 1 * 128 + a] = f2bf(dy * i1);
    xrow[256 + 2 * 128 + a] = f2bf(dz * i2);
    xrow[256 + 3 * 128 + a] = f2bf(dist * i3);
}

// ---------------- bf16 MFMA GEMM: C = act(A @ Bt^T + bias) ----------------
// A  : [M, K] bf16 row-major (K = 768)
// Bt : [N, K] bf16 row-major (pre-transposed weight)
// Tile 128x128, BK=32, 4 waves (2x2), each wave 64x64 via 4x4 16x16x32 MFMA.
// Grid: (N/128, M/128) with n-tile fastest for A-tile L2 reuse.
template <bool RELU, bool OUT_BF16>
__global__ __launch_bounds__(256) void gemm_bt(
    const unsigned short* __restrict__ A,
    const unsigned short* __restrict__ Bt,
    const float* __restrict__ bias,
    void* __restrict__ Cout,
    int K, int N)
{
    __shared__ unsigned short sA[128 * 32];
    __shared__ unsigned short sB[128 * 32];

    const int n0 = blockIdx.x * 128;
    const int m0 = blockIdx.y * 128;
    const int tid = threadIdx.x;
    const int lane = tid & 63;
    const int wave = tid >> 6;
    const int wr = wave >> 1, wc = wave & 1;

    f32x4 acc[4][4] = {};

    // staging: each thread stages 16 elems (2x short8) of A and of B per K-step
    const int srow = tid >> 1;            // 0..127
    const int kc0  = (tid & 1) * 2;       // logical 8-elem chunk {0,2}
    const int pc0  = kc0 ^ (srow & 3);    // XOR swizzle (phys chunk)
    const int pc1  = (kc0 + 1) ^ (srow & 3);
    const unsigned short* Ag = A  + (size_t)(m0 + srow) * K + kc0 * 8;
    const unsigned short* Bg = Bt + (size_t)(n0 + srow) * K + kc0 * 8;
    unsigned short* sA0 = &sA[srow * 32 + pc0 * 8];
    unsigned short* sA1 = &sA[srow * 32 + pc1 * 8];
    unsigned short* sB0 = &sB[srow * 32 + pc0 * 8];
    unsigned short* sB1 = &sB[srow * 32 + pc1 * 8];

    const int rsel = lane & 15;
    const int kb   = lane >> 4;           // logical chunk index 0..3

    for (int kt = 0; kt < K; kt += 32) {
        short8 av0 = *(const short8*)(Ag + kt);
        short8 av1 = *(const short8*)(Ag + kt + 8);
        short8 bv0 = *(const short8*)(Bg + kt);
        short8 bv1 = *(const short8*)(Bg + kt + 8);
        *(short8*)sA0 = av0;
        *(short8*)sA1 = av1;
        *(short8*)sB0 = bv0;
        *(short8*)sB1 = bv1;
        __syncthreads();

        short8 aF[4], bF[4];
#pragma unroll
        for (int i = 0; i < 4; i++) {
            const int arow = wr * 64 + i * 16 + rsel;
            const int brow = wc * 64 + i * 16 + rsel;
            aF[i] = *(const short8*)&sA[arow * 32 + (kb ^ (arow & 3)) * 8];
            bF[i] = *(const short8*)&sB[brow * 32 + (kb ^ (brow & 3)) * 8];
        }
#pragma unroll
        for (int i = 0; i < 4; i++)
#pragma unroll
            for (int j = 0; j < 4; j++)
                acc[i][j] = __builtin_amdgcn_mfma_f32_16x16x32_bf16(aF[i], bF[j], acc[i][j], 0, 0, 0);
        __syncthreads();
    }

    // epilogue: C/D layout (m89): col = lane&15, row = (lane>>4)*4 + reg
    const int crow = (lane >> 4) * 4;
    const int ccol = lane & 15;
#pragma unroll
    for (int j = 0; j < 4; j++) {
        const int col = n0 + wc * 64 + j * 16 + ccol;
        const float bv = bias[col];
#pragma unroll
        for (int i = 0; i < 4; i++) {
#pragma unroll
            for (int rg = 0; rg < 4; rg++) {
                const int row = m0 + wr * 64 + i * 16 + crow + rg;
                float v = acc[i][j][rg] + bv;
                if (RELU) v = fmaxf(v, 0.0f);
                if (OUT_BF16) {
                    ((unsigned short*)Cout)[(size_t)row * N + col] = f2bf(v);
                } else {
                    ((float*)Cout)[(size_t)row * N + col] = v;
                }
            }
        }
    }
}

extern "C" void kernel_launch(void* const* d_in, const int* in_sizes, int n_in,
                              void* d_out, int out_size, void* d_ws, size_t ws_size,
                              hipStream_t stream) {
    const float* feat0 = (const float*)d_in[0];
    const float* feat1 = (const float*)d_in[1];
    const float* pts0  = (const float*)d_in[2];
    const float* pts1  = (const float*)d_in[3];
    const int*   ids0  = (const int*)d_in[4];
    const int*   ids1  = (const int*)d_in[5];
    const float* W1    = (const float*)d_in[6];
    const float* b1    = (const float*)d_in[7];
    const float* W2    = (const float*)d_in[8];
    const float* b2    = (const float*)d_in[9];
    float* out = (float*)d_out;

    char* ws = (char*)d_ws;
    // layout (bytes): xw [38400*768]*2 = 58,982,400 ; h same ; W1T 1,179,648 ; W2T 393,216
    unsigned short* xw  = (unsigned short*)(ws);
    unsigned short* h   = (unsigned short*)(ws + 58982400);
    unsigned short* w1t = (unsigned short*)(ws + 117964800);
    unsigned short* w2t = (unsigned short*)(ws + 119144448);

    dim3 tb(32, 32);
    transpose_to_bf16<<<dim3(768 / 32, 768 / 32), tb, 0, stream>>>(W1, w1t, 768, 768);
    transpose_to_bf16<<<dim3(256 / 32, 768 / 32), tb, 0, stream>>>(W2, w2t, 768, 256);

    struct_pack<<<38400, 128, 0, stream>>>(feat0, feat1, pts0, pts1, ids0, ids1, xw);

    // GEMM1: h = relu(x @ W1 + b1)   M=38400, N=768, K=768
    gemm_bt<true, true><<<dim3(6, 300), 256, 0, stream>>>(xw, w1t, b1, (void*)h, 768, 768);
    // GEMM2: out = h @ W2 + b2       M=38400, N=256, K=768
    gemm_bt<false, false><<<dim3(2, 300), 256, 0, stream>>>(h, w2t, b2, (void*)out, 768, 256);
}

// Round 2
// 137.129 us; speedup vs baseline: 1.1452x; 1.1452x over previous
//
#include <hip/hip_runtime.h>
#include <stdint.h>
#include <stddef.h>

typedef __attribute__((ext_vector_type(8))) short short8;
typedef __attribute__((ext_vector_type(4))) float f32x4;

#define GLDS16(gp, lp)                                                        \
    __builtin_amdgcn_global_load_lds(                                         \
        (const __attribute__((address_space(1))) void*)(gp),                  \
        (__attribute__((address_space(3))) void*)(lp), 16, 0, 0)

__device__ __forceinline__ unsigned short f2bf(float f) {
    union { float f; uint32_t u; } v;
    v.f = f;
    uint32_t u = v.u;
    u += 0x7FFFu + ((u >> 16) & 1u);
    return (unsigned short)(u >> 16);
}

// ---------------- weight prep: transpose fp32 [R][C] -> bf16 [C][R] ----------------
__global__ __launch_bounds__(1024) void transpose_to_bf16(
    const float* __restrict__ src, unsigned short* __restrict__ dst, int R, int C)
{
    __shared__ float tile[32][33];
    const int c0 = blockIdx.x * 32, r0 = blockIdx.y * 32;
    const int tx = threadIdx.x, ty = threadIdx.y;
    tile[ty][tx] = src[(size_t)(r0 + ty) * C + (c0 + tx)];
    __syncthreads();
    dst[(size_t)(c0 + ty) * R + (r0 + tx)] = f2bf(tile[tx][ty]);
}

// ---------------- structural features + pack x = [feat | s] as bf16 ----------------
__global__ __launch_bounds__(128) void struct_pack(
    const float* __restrict__ feat0, const float* __restrict__ feat1,
    const float* __restrict__ pts0,  const float* __restrict__ pts1,
    const int* __restrict__ ids0,    const int* __restrict__ ids1,
    unsigned short* __restrict__ xw)
{
    const int m = blockIdx.x;
    const int t = m / 19200;
    const int r = m % 19200;
    const int n = r / 4800;
    const int l = r % 4800;
    const float* feat = t ? feat1 : feat0;
    const float* pts  = (t ? pts1 : pts0) + (size_t)n * (307200 * 3);
    const int*   ids  = (t ? ids1 : ids0) + n * 128;
    const int a = threadIdx.x;

    const int lr = l / 80, lc = l % 80;
    const int p  = (lr * 8) * 640 + lc * 8;
    const float cx = pts[p * 3 + 0], cy = pts[p * 3 + 1], cz = pts[p * 3 + 2];

    const int id = ids[a];
    const float ax = pts[id * 3 + 0], ay = pts[id * 3 + 1], az = pts[id * 3 + 2];
    const float dx = cx - ax, dy = cy - ay, dz = cz - az;
    const float dist = dx * dx + dy * dy + dz * dz;

    __shared__ float red[4][128];
    red[0][a] = fabsf(dx);
    red[1][a] = fabsf(dy);
    red[2][a] = fabsf(dz);
    red[3][a] = dist;
    __syncthreads();
    for (int off = 64; off > 0; off >>= 1) {
        if (a < off) {
            red[0][a] += red[0][a + off];
            red[1][a] += red[1][a + off];
            red[2][a] += red[2][a + off];
            red[3][a] += red[3][a + off];
        }
        __syncthreads();
    }
    const float i0 = 1.0f / red[0][0];
    const float i1 = 1.0f / red[1][0];
    const float i2 = 1.0f / red[2][0];
    const float i3 = 1.0f / red[3][0];

    unsigned short* xrow = xw + (size_t)m * 768;
    const float* frow = feat + (size_t)(n * 4800 + l) * 256;
    xrow[a]        = f2bf(frow[a]);
    xrow[a + 128]  = f2bf(frow[a + 128]);
    xrow[256 + 0 * 128 + a] = f2bf(dx * i0);
    xrow[256 + 1 * 128 + a] = f2bf(dy * i1);
    xrow[256 + 2 * 128 + a] = f2bf(dz * i2);
    xrow[256 + 3 * 128 + a] = f2bf(dist * i3);
}

// ---------------- bf16 MFMA GEMM (m97 structure): C = act(A @ Bt^T + bias) ----------------
// A  : [M, K] bf16 row-major; Bt : [N, K] bf16 row-major (pre-transposed weight)
// Tile 128x128, BK=64, 4 waves (2x2), each wave 64x64 via 4x4 16x16x32 MFMA.
// global_load_lds (16B/lane) into linear LDS; XOR swizzle (chunk ^= row&7) applied on the
// GLOBAL source address (m173) so ds_read_b128 fragment reads are 2-way (free).
// 1-D grid with bijective XCD swizzle (nwg % 8 == 0): works sharing an A-panel -> same XCD L2.
template <bool RELU, bool OUT_BF16>
__global__ __launch_bounds__(256) void gemm_lds(
    const unsigned short* __restrict__ A,
    const unsigned short* __restrict__ Bt,
    const float* __restrict__ bias,
    void* __restrict__ Cout,
    int K, int N, int ntx, int q8)
{
    __shared__ unsigned short sA[128 * 64];
    __shared__ unsigned short sB[128 * 64];

    const int bid = blockIdx.x;
    const int w = (bid & 7) * q8 + (bid >> 3);
    const int n0 = (w % ntx) * 128;
    const int m0 = (w / ntx) * 128;

    const int tid = threadIdx.x;
    const int lane = tid & 63;
    const int wv = tid >> 6;
    const int wr = wv >> 1, wc = wv & 1;

    // ---- staging addressing: wave wv, inst i covers rows (wv*4+i)*8 .. +8 (1 KB each)
    // lane l writes LDS bytes base + l*16  ->  row lr=l>>3, phys chunk l&7.
    // global chunk kc = (l&7) ^ lr  (inverse of read-side swizzle).
    const int lr = lane >> 3;
    const int kc = (lane & 7) ^ lr;
    const unsigned short* gA[4];
    const unsigned short* gB[4];
    unsigned short* lA[4];
    unsigned short* lB[4];
#pragma unroll
    for (int i = 0; i < 4; i++) {
        const int rloc = (wv * 4 + i) * 8 + lr;
        gA[i] = A  + (size_t)(m0 + rloc) * K + kc * 8;
        gB[i] = Bt + (size_t)(n0 + rloc) * K + kc * 8;
        lA[i] = &sA[(wv * 4 + i) * 8 * 64];
        lB[i] = &sB[(wv * 4 + i) * 8 * 64];
    }

    const int rsel = lane & 15;
    const int kbh  = lane >> 4;    // 16B chunk index within 64B half-k

    f32x4 acc[4][4] = {};

    for (int kt = 0; kt < K; kt += 64) {
#pragma unroll
        for (int i = 0; i < 4; i++) {
            GLDS16(gA[i] + kt, lA[i]);
            GLDS16(gB[i] + kt, lB[i]);
        }
        __syncthreads();   // compiler drains vmcnt(0) before barrier -> LDS ready

#pragma unroll
        for (int ks = 0; ks < 2; ks++) {
            short8 aF[4], bF[4];
#pragma unroll
            for (int i = 0; i < 4; i++) {
                const int arow = wr * 64 + i * 16 + rsel;
                const int brow = wc * 64 + i * 16 + rsel;
                aF[i] = *(const short8*)&sA[arow * 64 + (((ks * 4 + kbh) ^ (arow & 7)) * 8)];
                bF[i] = *(const short8*)&sB[brow * 64 + (((ks * 4 + kbh) ^ (brow & 7)) * 8)];
            }
#pragma unroll
            for (int i = 0; i < 4; i++)
#pragma unroll
                for (int j = 0; j < 4; j++)
                    acc[i][j] = __builtin_amdgcn_mfma_f32_16x16x32_bf16(aF[i], bF[j], acc[i][j], 0, 0, 0);
        }
        __syncthreads();   // protect LDS from next iteration's stores
    }

    // epilogue: C/D layout (m89): col = lane&15, row = (lane>>4)*4 + reg
    const int crow = (lane >> 4) * 4;
    const int ccol = lane & 15;
#pragma unroll
    for (int j = 0; j < 4; j++) {
        const int col = n0 + wc * 64 + j * 16 + ccol;
        const float bv = bias[col];
#pragma unroll
        for (int i = 0; i < 4; i++) {
#pragma unroll
            for (int rg = 0; rg < 4; rg++) {
                const int row = m0 + wr * 64 + i * 16 + crow + rg;
                float v = acc[i][j][rg] + bv;
                if (RELU) v = fmaxf(v, 0.0f);
                if (OUT_BF16) {
                    ((unsigned short*)Cout)[(size_t)row * N + col] = f2bf(v);
                } else {
                    ((float*)Cout)[(size_t)row * N + col] = v;
                }
            }
        }
    }
}

extern "C" void kernel_launch(void* const* d_in, const int* in_sizes, int n_in,
                              void* d_out, int out_size, void* d_ws, size_t ws_size,
                              hipStream_t stream) {
    const float* feat0 = (const float*)d_in[0];
    const float* feat1 = (const float*)d_in[1];
    const float* pts0  = (const float*)d_in[2];
    const float* pts1  = (const float*)d_in[3];
    const int*   ids0  = (const int*)d_in[4];
    const int*   ids1  = (const int*)d_in[5];
    const float* W1    = (const float*)d_in[6];
    const float* b1    = (const float*)d_in[7];
    const float* W2    = (const float*)d_in[8];
    const float* b2    = (const float*)d_in[9];
    float* out = (float*)d_out;

    char* ws = (char*)d_ws;
    // layout (bytes): xw [38400*768]*2 = 58,982,400 ; h same ; W1T 1,179,648 ; W2T 393,216
    unsigned short* xw  = (unsigned short*)(ws);
    unsigned short* h   = (unsigned short*)(ws + 58982400);
    unsigned short* w1t = (unsigned short*)(ws + 117964800);
    unsigned short* w2t = (unsigned short*)(ws + 119144448);

    dim3 tb(32, 32);
    transpose_to_bf16<<<dim3(768 / 32, 768 / 32), tb, 0, stream>>>(W1, w1t, 768, 768);
    transpose_to_bf16<<<dim3(256 / 32, 768 / 32), tb, 0, stream>>>(W2, w2t, 768, 256);

    struct_pack<<<38400, 128, 0, stream>>>(feat0, feat1, pts0, pts1, ids0, ids1, xw);

    // GEMM1: h = relu(x @ W1 + b1)   M=38400, N=768, K=768  -> nwg = 6*300 = 1800, q8 = 225
    gemm_lds<true, true><<<1800, 256, 0, stream>>>(xw, w1t, b1, (void*)h, 768, 768, 6, 225);
    // GEMM2: out = h @ W2 + b2       M=38400, N=256, K=768  -> nwg = 2*300 = 600, q8 = 75
    gemm_lds<false, false><<<600, 256, 0, stream>>>(h, w2t, b2, (void*)out, 768, 256, 2, 75);
}

// Round 3
// 129.382 us; speedup vs baseline: 1.2138x; 1.0599x over previous
//
#include <hip/hip_runtime.h>
#include <stdint.h>
#include <stddef.h>

typedef __attribute__((ext_vector_type(8))) short short8;
typedef __attribute__((ext_vector_type(4))) short short4v;
typedef __attribute__((ext_vector_type(4))) float f32x4;

#define GLDS16(gp, lp)                                                        \
    __builtin_amdgcn_global_load_lds(                                         \
        (const __attribute__((address_space(1))) void*)(gp),                  \
        (__attribute__((address_space(3))) void*)(lp), 16, 0, 0)

__device__ __forceinline__ unsigned short f2bf(float f) {
    union { float f; uint32_t u; } v;
    v.f = f;
    uint32_t u = v.u;
    u += 0x7FFFu + ((u >> 16) & 1u);
    return (unsigned short)(u >> 16);
}

// ---------------- weight prep: transpose fp32 [R][C] -> bf16 [C][R] ----------------
__global__ __launch_bounds__(1024) void transpose_to_bf16(
    const float* __restrict__ src, unsigned short* __restrict__ dst, int R, int C)
{
    __shared__ float tile[32][33];
    const int c0 = blockIdx.x * 32, r0 = blockIdx.y * 32;
    const int tx = threadIdx.x, ty = threadIdx.y;
    tile[ty][tx] = src[(size_t)(r0 + ty) * C + (c0 + tx)];
    __syncthreads();
    dst[(size_t)(c0 + ty) * R + (r0 + tx)] = f2bf(tile[tx][ty]);
}

// ---------------- structural features + pack x = [feat | s] as bf16 ----------------
// 1 wave per (t,n,l); lane a handles anchors a and a+64; shfl_xor reduce (no barriers).
__global__ __launch_bounds__(64) void struct_pack(
    const float* __restrict__ feat0, const float* __restrict__ feat1,
    const float* __restrict__ pts0,  const float* __restrict__ pts1,
    const int* __restrict__ ids0,    const int* __restrict__ ids1,
    unsigned short* __restrict__ xw)
{
    const int m = blockIdx.x;
    const int t = m / 19200;
    const int r = m % 19200;
    const int n = r / 4800;
    const int l = r % 4800;
    const float* feat = t ? feat1 : feat0;
    const float* pts  = (t ? pts1 : pts0) + (size_t)n * (307200 * 3);
    const int*   ids  = (t ? ids1 : ids0) + n * 128;
    const int a = threadIdx.x;  // 0..63

    const int lr = l / 80, lc = l % 80;
    const int p  = (lr * 8) * 640 + lc * 8;
    const float cx = pts[p * 3 + 0], cy = pts[p * 3 + 1], cz = pts[p * 3 + 2];

    const int id0 = ids[a], id1 = ids[a + 64];
    const float d0x = cx - pts[id0 * 3 + 0];
    const float d0y = cy - pts[id0 * 3 + 1];
    const float d0z = cz - pts[id0 * 3 + 2];
    const float d0d = d0x * d0x + d0y * d0y + d0z * d0z;
    const float d1x = cx - pts[id1 * 3 + 0];
    const float d1y = cy - pts[id1 * 3 + 1];
    const float d1z = cz - pts[id1 * 3 + 2];
    const float d1d = d1x * d1x + d1y * d1y + d1z * d1z;

    float p0 = fabsf(d0x) + fabsf(d1x);
    float p1 = fabsf(d0y) + fabsf(d1y);
    float p2 = fabsf(d0z) + fabsf(d1z);
    float p3 = d0d + d1d;
#pragma unroll
    for (int off = 32; off; off >>= 1) {
        p0 += __shfl_xor(p0, off);
        p1 += __shfl_xor(p1, off);
        p2 += __shfl_xor(p2, off);
        p3 += __shfl_xor(p3, off);
    }
    const float i0 = 1.0f / p0, i1 = 1.0f / p1, i2 = 1.0f / p2, i3 = 1.0f / p3;

    unsigned short* xrow = xw + (size_t)m * 768;
    const float* frow = feat + (size_t)(n * 4800 + l) * 256;
    const float4 fv = ((const float4*)frow)[a];
    short4v s4;
    s4.x = (short)f2bf(fv.x); s4.y = (short)f2bf(fv.y);
    s4.z = (short)f2bf(fv.z); s4.w = (short)f2bf(fv.w);
    *(short4v*)(xrow + a * 4) = s4;

    xrow[256 + 0 * 128 + a]      = f2bf(d0x * i0);
    xrow[256 + 0 * 128 + a + 64] = f2bf(d1x * i0);
    xrow[256 + 1 * 128 + a]      = f2bf(d0y * i1);
    xrow[256 + 1 * 128 + a + 64] = f2bf(d1y * i1);
    xrow[256 + 2 * 128 + a]      = f2bf(d0z * i2);
    xrow[256 + 2 * 128 + a + 64] = f2bf(d1z * i2);
    xrow[256 + 3 * 128 + a]      = f2bf(d0d * i3);
    xrow[256 + 3 * 128 + a + 64] = f2bf(d1d * i3);
}

// ---------------- 8-wave 4-phase counted-vmcnt MFMA GEMM ----------------
// C = act(A @ Bt^T + bias). A:[M,K] bf16, Bt:[N,K] bf16 (pre-transposed weight).
// BM=256, BN=128, BK=64. 8 waves (4M x 2N), wave tile 64x64 (4x4 frags 16x16x32).
// LDS: ring of 3 buffers x (A 32KB | B 16KB) = 144KB dynamic.
// Staging: global_load_lds 16B, linear LDS dest, pre-swizzled global source
// (chunk kc = (lane&7) ^ (lane>>3)); read side chunk = (ks*4+kbh) ^ (row&7)
// -> 0 bank conflicts (measured round 2).
// Schedule: tile t computes from buf[t%3] in 4 phases, stages tile t+2 into
// buf[(t+2)%3] (last read in tile t-1, sealed by that boundary barrier -> no race).
// Boundary: s_waitcnt vmcnt(6) (tile t+2's 6 loads stay in flight) + raw s_barrier.
template <bool RELU, bool OUT_BF16>
__global__ __launch_bounds__(512, 2) void gemm_8ph(
    const unsigned short* __restrict__ A,
    const unsigned short* __restrict__ Bt,
    const float* __restrict__ bias,
    void* __restrict__ Cout,
    int K, int N, int ntx, int q8, int r8)
{
    extern __shared__ char lds[];
    const int nt = K >> 6;

    const int bid = blockIdx.x;
    const int xcd = bid & 7, idx = bid >> 3;
    const int w = (xcd < r8 ? xcd * (q8 + 1) : r8 * (q8 + 1) + (xcd - r8) * q8) + idx;
    const int n0 = (w % ntx) * 128;
    const int m0 = (w / ntx) * 256;

    const int tid = threadIdx.x;
    const int lane = tid & 63;
    const int wv = tid >> 6;       // 0..7
    const int wr = wv >> 1;        // 0..3 (M)
    const int wc = wv & 1;         // 0..1 (N)

    // staging addresses (pre-swizzled global source)
    const int slr = lane >> 3;
    const int kc  = (lane & 7) ^ slr;
    const unsigned short* gA = A  + (size_t)(m0 + wv * 8 + slr) * K + kc * 8;
    const unsigned short* gB = Bt + (size_t)(n0 + wv * 8 + slr) * K + kc * 8;
    const int ldsW = wv * 1024;

    auto stageA = [&](int buf, int i, int kt) {
        GLDS16(gA + (size_t)i * 64 * K + kt, lds + buf * 49152 + i * 8192 + ldsW);
    };
    auto stageB = [&](int buf, int j, int kt) {
        GLDS16(gB + (size_t)j * 64 * K + kt, lds + buf * 49152 + 32768 + j * 8192 + ldsW);
    };

    // read-side addressing
    const int rsel = lane & 15;
    const int kbh  = lane >> 4;
    const int ck0 = ((kbh) ^ (rsel & 7)) * 16;
    const int ck1 = ((4 + kbh) ^ (rsel & 7)) * 16;
    const int aRowB = (wr * 64 + rsel) * 128;
    const int bRowB = (wc * 64 + rsel) * 128;

    auto LDA = [&](int buf, int mi, int ks) -> short8 {
        return *(const short8*)(lds + buf * 49152 + aRowB + mi * 2048 + (ks ? ck1 : ck0));
    };
    auto LDB = [&](int buf, int ni, int ks) -> short8 {
        return *(const short8*)(lds + buf * 49152 + 32768 + bRowB + ni * 2048 + (ks ? ck1 : ck0));
    };

    f32x4 acc[4][4] = {};
    short8 aF[4][2], bF[4][2];

    // prologue: stage tiles 0 and 1 (6 insts each)
    {
        stageA(0, 0, 0); stageA(0, 1, 0); stageA(0, 2, 0); stageA(0, 3, 0);
        stageB(0, 0, 0); stageB(0, 1, 0);
        if (nt > 1) {
            stageA(1, 0, 64); stageA(1, 1, 64); stageA(1, 2, 64); stageA(1, 3, 64);
            stageB(1, 0, 64); stageB(1, 1, 64);
        }
    }
    asm volatile("s_waitcnt vmcnt(6)" ::: "memory");
    __builtin_amdgcn_s_barrier();

    for (int t = 0; t < nt; ++t) {
        const int cb = t % 3;
        const int sb = (t + 2) % 3;
        const int kt2 = (t + 2) << 6;
        const bool st = (t + 2) < nt;

        // ---- phase 0: read a(0,1), b(0,1); stage A0,A1; mfma q(mi01 x ni01)
        aF[0][0] = LDA(cb, 0, 0); aF[0][1] = LDA(cb, 0, 1);
        aF[1][0] = LDA(cb, 1, 0); aF[1][1] = LDA(cb, 1, 1);
        bF[0][0] = LDB(cb, 0, 0); bF[0][1] = LDB(cb, 0, 1);
        bF[1][0] = LDB(cb, 1, 0); bF[1][1] = LDB(cb, 1, 1);
        if (st) { stageA(sb, 0, kt2); stageA(sb, 1, kt2); }
        __builtin_amdgcn_s_barrier();
        __builtin_amdgcn_s_setprio(1);
#pragma unroll
        for (int i = 0; i < 2; i++)
#pragma unroll
            for (int j = 0; j < 2; j++)
#pragma unroll
                for (int ks = 0; ks < 2; ks++)
                    acc[i][j] = __builtin_amdgcn_mfma_f32_16x16x32_bf16(aF[i][ks], bF[j][ks], acc[i][j], 0, 0, 0);
        __builtin_amdgcn_s_setprio(0);
        __builtin_amdgcn_s_barrier();

        // ---- phase 1: read a(2,3); stage A2,A3; mfma q(mi23 x ni01)
        aF[2][0] = LDA(cb, 2, 0); aF[2][1] = LDA(cb, 2, 1);
        aF[3][0] = LDA(cb, 3, 0); aF[3][1] = LDA(cb, 3, 1);
        if (st) { stageA(sb, 2, kt2); stageA(sb, 3, kt2); }
        __builtin_amdgcn_s_barrier();
        __builtin_amdgcn_s_setprio(1);
#pragma unroll
        for (int i = 2; i < 4; i++)
#pragma unroll
            for (int j = 0; j < 2; j++)
#pragma unroll
                for (int ks = 0; ks < 2; ks++)
                    acc[i][j] = __builtin_amdgcn_mfma_f32_16x16x32_bf16(aF[i][ks], bF[j][ks], acc[i][j], 0, 0, 0);
        __builtin_amdgcn_s_setprio(0);
        __builtin_amdgcn_s_barrier();

        // ---- phase 2: read b(2,3); stage B0; mfma q(mi01 x ni23)
        bF[2][0] = LDB(cb, 2, 0); bF[2][1] = LDB(cb, 2, 1);
        bF[3][0] = LDB(cb, 3, 0); bF[3][1] = LDB(cb, 3, 1);
        if (st) { stageB(sb, 0, kt2); }
        __builtin_amdgcn_s_barrier();
        __builtin_amdgcn_s_setprio(1);
#pragma unroll
        for (int i = 0; i < 2; i++)
#pragma unroll
            for (int j = 2; j < 4; j++)
#pragma unroll
                for (int ks = 0; ks < 2; ks++)
                    acc[i][j] = __builtin_amdgcn_mfma_f32_16x16x32_bf16(aF[i][ks], bF[j][ks], acc[i][j], 0, 0, 0);
        __builtin_amdgcn_s_setprio(0);
        __builtin_amdgcn_s_barrier();

        // ---- phase 3: stage B1; mfma q(mi23 x ni23)
        if (st) { stageB(sb, 1, kt2); }
        __builtin_amdgcn_s_barrier();
        __builtin_amdgcn_s_setprio(1);
#pragma unroll
        for (int i = 2; i < 4; i++)
#pragma unroll
            for (int j = 2; j < 4; j++)
#pragma unroll
                for (int ks = 0; ks < 2; ks++)
                    acc[i][j] = __builtin_amdgcn_mfma_f32_16x16x32_bf16(aF[i][ks], bF[j][ks], acc[i][j], 0, 0, 0);
        __builtin_amdgcn_s_setprio(0);

        // ---- tile boundary: counted vmcnt keeps tile t+2's loads in flight
        if (st) { asm volatile("s_waitcnt vmcnt(6)" ::: "memory"); }
        else    { asm volatile("s_waitcnt vmcnt(0)" ::: "memory"); }
        __builtin_amdgcn_s_barrier();
    }

    // epilogue: C/D layout (m89): col = lane&15, row = (lane>>4)*4 + reg
    const int crow = (lane >> 4) * 4;
    const int ccol = lane & 15;
#pragma unroll
    for (int j = 0; j < 4; j++) {
        const int col = n0 + wc * 64 + j * 16 + ccol;
        const float bv = bias[col];
#pragma unroll
        for (int i = 0; i < 4; i++) {
#pragma unroll
            for (int rg = 0; rg < 4; rg++) {
                const int row = m0 + wr * 64 + i * 16 + crow + rg;
                float v = acc[i][j][rg] + bv;
                if (RELU) v = fmaxf(v, 0.0f);
                if (OUT_BF16) {
                    ((unsigned short*)Cout)[(size_t)row * N + col] = f2bf(v);
                } else {
                    ((float*)Cout)[(size_t)row * N + col] = v;
                }
            }
        }
    }
}

extern "C" void kernel_launch(void* const* d_in, const int* in_sizes, int n_in,
                              void* d_out, int out_size, void* d_ws, size_t ws_size,
                              hipStream_t stream) {
    const float* feat0 = (const float*)d_in[0];
    const float* feat1 = (const float*)d_in[1];
    const float* pts0  = (const float*)d_in[2];
    const float* pts1  = (const float*)d_in[3];
    const int*   ids0  = (const int*)d_in[4];
    const int*   ids1  = (const int*)d_in[5];
    const float* W1    = (const float*)d_in[6];
    const float* b1    = (const float*)d_in[7];
    const float* W2    = (const float*)d_in[8];
    const float* b2    = (const float*)d_in[9];
    float* out = (float*)d_out;

    char* ws = (char*)d_ws;
    unsigned short* xw  = (unsigned short*)(ws);
    unsigned short* h   = (unsigned short*)(ws + 58982400);
    unsigned short* w1t = (unsigned short*)(ws + 117964800);
    unsigned short* w2t = (unsigned short*)(ws + 119144448);

    const int LDS_BYTES = 147456;
    (void)hipFuncSetAttribute((const void*)&gemm_8ph<true, true>,
                              hipFuncAttributeMaxDynamicSharedMemorySize, LDS_BYTES);
    (void)hipFuncSetAttribute((const void*)&gemm_8ph<false, false>,
                              hipFuncAttributeMaxDynamicSharedMemorySize, LDS_BYTES);

    dim3 tb(32, 32);
    transpose_to_bf16<<<dim3(768 / 32, 768 / 32), tb, 0, stream>>>(W1, w1t, 768, 768);
    transpose_to_bf16<<<dim3(256 / 32, 768 / 32), tb, 0, stream>>>(W2, w2t, 768, 256);

    struct_pack<<<38400, 64, 0, stream>>>(feat0, feat1, pts0, pts1, ids0, ids1, xw);

    // GEMM1: h = relu(x @ W1 + b1)  M=38400, N=768 -> tiles 150 x 6 = 900 wg (q8=112, r8=4)
    gemm_8ph<true, true><<<900, 512, LDS_BYTES, stream>>>(xw, w1t, b1, (void*)h, 768, 768, 6, 112, 4);
    // GEMM2: out = h @ W2 + b2      M=38400, N=256 -> tiles 150 x 2 = 300 wg (q8=37, r8=4)
    gemm_8ph<false, false><<<300, 512, LDS_BYTES, stream>>>(h, w2t, b2, (void*)out, 768, 256, 2, 37, 4);
}

// Round 4
// 125.768 us; speedup vs baseline: 1.2487x; 1.0287x over previous
//
#include <hip/hip_runtime.h>
#include <stdint.h>
#include <stddef.h>

typedef __attribute__((ext_vector_type(8))) short short8;
typedef __attribute__((ext_vector_type(4))) short short4v;
typedef __attribute__((ext_vector_type(4))) float f32x4;

#define GLDS16(gp, lp)                                                        \
    __builtin_amdgcn_global_load_lds(                                         \
        (const __attribute__((address_space(1))) void*)(gp),                  \
        (__attribute__((address_space(3))) void*)(lp), 16, 0, 0)

__device__ __forceinline__ unsigned short f2bf(float f) {
    union { float f; uint32_t u; } v;
    v.f = f;
    uint32_t u = v.u;
    u += 0x7FFFu + ((u >> 16) & 1u);
    return (unsigned short)(u >> 16);
}

// ---------------- weight prep: transpose fp32 [R][C] -> bf16 [C][R] ----------------
__global__ __launch_bounds__(1024) void transpose_to_bf16(
    const float* __restrict__ src, unsigned short* __restrict__ dst, int R, int C)
{
    __shared__ float tile[32][33];
    const int c0 = blockIdx.x * 32, r0 = blockIdx.y * 32;
    const int tx = threadIdx.x, ty = threadIdx.y;
    tile[ty][tx] = src[(size_t)(r0 + ty) * C + (c0 + tx)];
    __syncthreads();
    dst[(size_t)(c0 + ty) * R + (r0 + tx)] = f2bf(tile[tx][ty]);
}

// ---------------- structural features + pack x = [feat | s] as bf16 ----------------
__global__ __launch_bounds__(64) void struct_pack(
    const float* __restrict__ feat0, const float* __restrict__ feat1,
    const float* __restrict__ pts0,  const float* __restrict__ pts1,
    const int* __restrict__ ids0,    const int* __restrict__ ids1,
    unsigned short* __restrict__ xw)
{
    const int m = blockIdx.x;
    const int t = m / 19200;
    const int r = m % 19200;
    const int n = r / 4800;
    const int l = r % 4800;
    const float* feat = t ? feat1 : feat0;
    const float* pts  = (t ? pts1 : pts0) + (size_t)n * (307200 * 3);
    const int*   ids  = (t ? ids1 : ids0) + n * 128;
    const int a = threadIdx.x;  // 0..63

    const int lr = l / 80, lc = l % 80;
    const int p  = (lr * 8) * 640 + lc * 8;
    const float cx = pts[p * 3 + 0], cy = pts[p * 3 + 1], cz = pts[p * 3 + 2];

    const int id0 = ids[a], id1 = ids[a + 64];
    const float d0x = cx - pts[id0 * 3 + 0];
    const float d0y = cy - pts[id0 * 3 + 1];
    const float d0z = cz - pts[id0 * 3 + 2];
    const float d0d = d0x * d0x + d0y * d0y + d0z * d0z;
    const float d1x = cx - pts[id1 * 3 + 0];
    const float d1y = cy - pts[id1 * 3 + 1];
    const float d1z = cz - pts[id1 * 3 + 2];
    const float d1d = d1x * d1x + d1y * d1y + d1z * d1z;

    float p0 = fabsf(d0x) + fabsf(d1x);
    float p1 = fabsf(d0y) + fabsf(d1y);
    float p2 = fabsf(d0z) + fabsf(d1z);
    float p3 = d0d + d1d;
#pragma unroll
    for (int off = 32; off; off >>= 1) {
        p0 += __shfl_xor(p0, off);
        p1 += __shfl_xor(p1, off);
        p2 += __shfl_xor(p2, off);
        p3 += __shfl_xor(p3, off);
    }
    const float i0 = 1.0f / p0, i1 = 1.0f / p1, i2 = 1.0f / p2, i3 = 1.0f / p3;

    unsigned short* xrow = xw + (size_t)m * 768;
    const float* frow = feat + (size_t)(n * 4800 + l) * 256;
    const float4 fv = ((const float4*)frow)[a];
    short4v s4;
    s4.x = (short)f2bf(fv.x); s4.y = (short)f2bf(fv.y);
    s4.z = (short)f2bf(fv.z); s4.w = (short)f2bf(fv.w);
    *(short4v*)(xrow + a * 4) = s4;

    xrow[256 + 0 * 128 + a]      = f2bf(d0x * i0);
    xrow[256 + 0 * 128 + a + 64] = f2bf(d1x * i0);
    xrow[256 + 1 * 128 + a]      = f2bf(d0y * i1);
    xrow[256 + 1 * 128 + a + 64] = f2bf(d1y * i1);
    xrow[256 + 2 * 128 + a]      = f2bf(d0z * i2);
    xrow[256 + 2 * 128 + a + 64] = f2bf(d1z * i2);
    xrow[256 + 3 * 128 + a]      = f2bf(d0d * i3);
    xrow[256 + 3 * 128 + a + 64] = f2bf(d1d * i3);
}

// ---------------- 8-wave 4-phase MFMA GEMM, m201 geometry ----------------
// C = act(A @ Bt^T + bias). A:[M,K] bf16, Bt:[N,K] bf16 (pre-transposed weight).
// Template: WRM x WRN wave grid (WRN = 1<<WRN_LOG, WRM = 8/WRN), wave tile (MI*16) x (NJ*16).
// BM = WRM*MI*16, BN = WRN*NJ*16, BK = 64.
// LDS: A ring-3 (stage t+2 ahead; HBM stream) + B ring-2 (stage t+1; L2-resident weights).
// Issue order within tile t: B(t+1) then A(t+2) -> boundary s_waitcnt vmcnt(4) keeps
// A(t+2)'s 4 loads in flight while guaranteeing A(t+1)+B(t+1) landed; + s_barrier makes
// that collective across waves. Never vmcnt(0) in steady state.
// Staging: global_load_lds 16B, linear LDS dest, pre-swizzled global k-chunk
// (kc = (lane&7) ^ (lane>>3)); read side chunk ((ks*4+kbh) ^ (row&7)) -> 0 bank conflicts
// (measured rounds 2-3).
template <int MI, int NJ, int WRN_LOG, bool RELU, bool OUT_BF16>
__global__ __launch_bounds__(512, 2) void gemm_t(
    const unsigned short* __restrict__ A,
    const unsigned short* __restrict__ Bt,
    const float* __restrict__ bias,
    void* __restrict__ Cout,
    int K, int N, int ntx, int q8, int r8)
{
    constexpr int WRN = 1 << WRN_LOG;
    constexpr int WRM = 8 / WRN;
    constexpr int BM = WRM * MI * 16;
    constexpr int BN = WRN * NJ * 16;
    constexpr int ASLOT = BM * 128;   // bytes per A tile buffer (64k * 2B rows)
    constexpr int BSLOT = BN * 128;
    constexpr int ALD = BM / 64;      // A loads per wave per tile (=4 for BM=256)
    constexpr int BLD = BN / 64;
    static_assert(ALD == 4, "vmcnt immediates assume 4 A-loads/wave/tile");

    extern __shared__ char lds[];
    const int nt = K >> 6;

    const int bid = blockIdx.x;
    const int xcd = bid & 7, idx = bid >> 3;
    const int w = (xcd < r8 ? xcd * (q8 + 1) : r8 * (q8 + 1) + (xcd - r8) * q8) + idx;
    const int n0 = (w % ntx) * BN;
    const int m0 = (w / ntx) * BM;

    const int tid = threadIdx.x;
    const int lane = tid & 63;
    const int wv = tid >> 6;
    const int wr = wv >> WRN_LOG;
    const int wc = wv & (WRN - 1);

    // staging (pre-swizzled global source, linear LDS dest)
    const int slr = lane >> 3;
    const int kc  = (lane & 7) ^ slr;
    const unsigned short* gA = A  + (size_t)(m0 + wv * 8 + slr) * K + kc * 8;
    const unsigned short* gB = Bt + (size_t)(n0 + wv * 8 + slr) * K + kc * 8;

    auto stA = [&](int slot, int i, int kt) {
        GLDS16(gA + (size_t)i * 64 * K + kt, lds + slot * ASLOT + (i * 64 + wv * 8) * 128);
    };
    auto stB = [&](int slot, int j, int kt) {
        GLDS16(gB + (size_t)j * 64 * K + kt, lds + 3 * ASLOT + slot * BSLOT + (j * 64 + wv * 8) * 128);
    };

    // read-side addressing
    const int rsel = lane & 15;
    const int kbh  = lane >> 4;
    const int ck0 = ((kbh) ^ (rsel & 7)) * 16;
    const int ck1 = ((4 + kbh) ^ (rsel & 7)) * 16;
    const int aRowB = (wr * (MI * 16) + rsel) * 128;
    const int bRowB = (wc * (NJ * 16) + rsel) * 128;

    auto LDA = [&](int slot, int mi, int ks) -> short8 {
        return *(const short8*)(lds + slot * ASLOT + aRowB + mi * 2048 + (ks ? ck1 : ck0));
    };
    auto LDB = [&](int slot, int nj, int ks) -> short8 {
        return *(const short8*)(lds + 3 * ASLOT + slot * BSLOT + bRowB + nj * 2048 + (ks ? ck1 : ck0));
    };

    f32x4 acc[MI][NJ] = {};
    short8 aF[MI / 2], bF[NJ];

    // ---- prologue: A(0), B(0), A(1); keep A(1) in flight
    {
#pragma unroll
        for (int i = 0; i < ALD; ++i) stA(0, i, 0);
#pragma unroll
        for (int j = 0; j < BLD; ++j) stB(0, j, 0);
        if (nt > 1) {
#pragma unroll
            for (int i = 0; i < ALD; ++i) stA(1, i, 64);
            asm volatile("s_waitcnt vmcnt(4)" ::: "memory");
        } else {
            asm volatile("s_waitcnt vmcnt(0)" ::: "memory");
        }
        __builtin_amdgcn_s_barrier();
    }

    int cb3 = 0;  // t % 3
    for (int t = 0; t < nt; ++t) {
        const int cb2 = t & 1;
        const int sb2 = cb2 ^ 1;
        int sa3 = cb3 + 2; if (sa3 >= 3) sa3 -= 3;
        const int kt1 = (t + 1) << 6;
        const int kt2 = (t + 2) << 6;
        const bool stb = (t + 1) < nt;
        const bool sta = (t + 2) < nt;

        // ---- phase 0: bF(ks0), aF[lo](ks0); stage B half 0; MFMA lo x all (ks0)
#pragma unroll
        for (int nj = 0; nj < NJ; ++nj) bF[nj] = LDB(cb2, nj, 0);
#pragma unroll
        for (int mi = 0; mi < MI / 2; ++mi) aF[mi] = LDA(cb3, mi, 0);
        if (stb) {
#pragma unroll
            for (int j = 0; j < BLD / 2; ++j) stB(sb2, j, kt1);
        }
        __builtin_amdgcn_s_barrier();
        __builtin_amdgcn_s_setprio(1);
#pragma unroll
        for (int mi = 0; mi < MI / 2; ++mi)
#pragma unroll
            for (int nj = 0; nj < NJ; ++nj)
                acc[mi][nj] = __builtin_amdgcn_mfma_f32_16x16x32_bf16(aF[mi], bF[nj], acc[mi][nj], 0, 0, 0);
        __builtin_amdgcn_s_setprio(0);
        __builtin_amdgcn_s_barrier();

        // ---- phase 1: aF[hi](ks0); stage B half 1; MFMA hi x all (ks0)
#pragma unroll
        for (int mi = 0; mi < MI / 2; ++mi) aF[mi] = LDA(cb3, MI / 2 + mi, 0);
        if (stb) {
#pragma unroll
            for (int j = BLD / 2; j < BLD; ++j) stB(sb2, j, kt1);
        }
        __builtin_amdgcn_s_barrier();
        __builtin_amdgcn_s_setprio(1);
#pragma unroll
        for (int mi = 0; mi < MI / 2; ++mi)
#pragma unroll
            for (int nj = 0; nj < NJ; ++nj)
                acc[MI / 2 + mi][nj] = __builtin_amdgcn_mfma_f32_16x16x32_bf16(aF[mi], bF[nj], acc[MI / 2 + mi][nj], 0, 0, 0);
        __builtin_amdgcn_s_setprio(0);
        __builtin_amdgcn_s_barrier();

        // ---- phase 2: bF(ks1), aF[lo](ks1); stage A half 0 (t+2); MFMA lo x all (ks1)
#pragma unroll
        for (int nj = 0; nj < NJ; ++nj) bF[nj] = LDB(cb2, nj, 1);
#pragma unroll
        for (int mi = 0; mi < MI / 2; ++mi) aF[mi] = LDA(cb3, mi, 1);
        if (sta) { stA(sa3, 0, kt2); stA(sa3, 1, kt2); }
        __builtin_amdgcn_s_barrier();
        __builtin_amdgcn_s_setprio(1);
#pragma unroll
        for (int mi = 0; mi < MI / 2; ++mi)
#pragma unroll
            for (int nj = 0; nj < NJ; ++nj)
                acc[mi][nj] = __builtin_amdgcn_mfma_f32_16x16x32_bf16(aF[mi], bF[nj], acc[mi][nj], 0, 0, 0);
        __builtin_amdgcn_s_setprio(0);
        __builtin_amdgcn_s_barrier();

        // ---- phase 3: aF[hi](ks1); stage A half 1 (t+2); MFMA hi x all (ks1)
#pragma unroll
        for (int mi = 0; mi < MI / 2; ++mi) aF[mi] = LDA(cb3, MI / 2 + mi, 1);
        if (sta) { stA(sa3, 2, kt2); stA(sa3, 3, kt2); }
        __builtin_amdgcn_s_barrier();
        __builtin_amdgcn_s_setprio(1);
#pragma unroll
        for (int mi = 0; mi < MI / 2; ++mi)
#pragma unroll
            for (int nj = 0; nj < NJ; ++nj)
                acc[MI / 2 + mi][nj] = __builtin_amdgcn_mfma_f32_16x16x32_bf16(aF[mi], bF[nj], acc[MI / 2 + mi][nj], 0, 0, 0);
        __builtin_amdgcn_s_setprio(0);

        // ---- tile boundary: counted vmcnt, collective via barrier
        if (t + 1 < nt) {
            if (t + 2 < nt) asm volatile("s_waitcnt vmcnt(4)" ::: "memory");
            else            asm volatile("s_waitcnt vmcnt(0)" ::: "memory");
            __builtin_amdgcn_s_barrier();
        }
        cb3 = (cb3 + 1 == 3) ? 0 : cb3 + 1;
    }

    // epilogue: C/D layout (m89): col = lane&15, row = (lane>>4)*4 + reg
    const int crow = (lane >> 4) * 4;
    const int ccol = lane & 15;
#pragma unroll
    for (int nj = 0; nj < NJ; ++nj) {
        const int col = n0 + wc * (NJ * 16) + nj * 16 + ccol;
        const float bv = bias[col];
#pragma unroll
        for (int mi = 0; mi < MI; ++mi) {
#pragma unroll
            for (int rg = 0; rg < 4; ++rg) {
                const int row = m0 + wr * (MI * 16) + mi * 16 + crow + rg;
                float v = acc[mi][nj][rg] + bv;
                if (RELU) v = fmaxf(v, 0.0f);
                if (OUT_BF16) {
                    ((unsigned short*)Cout)[(size_t)row * N + col] = f2bf(v);
                } else {
                    ((float*)Cout)[(size_t)row * N + col] = v;
                }
            }
        }
    }
}

extern "C" void kernel_launch(void* const* d_in, const int* in_sizes, int n_in,
                              void* d_out, int out_size, void* d_ws, size_t ws_size,
                              hipStream_t stream) {
    const float* feat0 = (const float*)d_in[0];
    const float* feat1 = (const float*)d_in[1];
    const float* pts0  = (const float*)d_in[2];
    const float* pts1  = (const float*)d_in[3];
    const int*   ids0  = (const int*)d_in[4];
    const int*   ids1  = (const int*)d_in[5];
    const float* W1    = (const float*)d_in[6];
    const float* b1    = (const float*)d_in[7];
    const float* W2    = (const float*)d_in[8];
    const float* b2    = (const float*)d_in[9];
    float* out = (float*)d_out;

    char* ws = (char*)d_ws;
    unsigned short* xw  = (unsigned short*)(ws);
    unsigned short* h   = (unsigned short*)(ws + 58982400);
    unsigned short* w1t = (unsigned short*)(ws + 117964800);
    unsigned short* w2t = (unsigned short*)(ws + 119144448);

    // GEMM1: 256x256 tile, waves 2Mx4N (wave tile 128x64): MI=8, NJ=4, WRN_LOG=2
    // LDS = 3*32KB (A ring) + 2*32KB (B ring) = 160KB
    const int LDS1 = 3 * 32768 + 2 * 32768;
    // GEMM2: 256x128 tile, waves 4Mx2N (wave tile 64x64): MI=4, NJ=4, WRN_LOG=1
    const int LDS2 = 3 * 32768 + 2 * 16384;
    (void)hipFuncSetAttribute((const void*)&gemm_t<8, 4, 2, true, true>,
                              hipFuncAttributeMaxDynamicSharedMemorySize, LDS1);
    (void)hipFuncSetAttribute((const void*)&gemm_t<4, 4, 1, false, false>,
                              hipFuncAttributeMaxDynamicSharedMemorySize, LDS2);

    dim3 tb(32, 32);
    transpose_to_bf16<<<dim3(768 / 32, 768 / 32), tb, 0, stream>>>(W1, w1t, 768, 768);
    transpose_to_bf16<<<dim3(256 / 32, 768 / 32), tb, 0, stream>>>(W2, w2t, 768, 256);

    struct_pack<<<38400, 64, 0, stream>>>(feat0, feat1, pts0, pts1, ids0, ids1, xw);

    // GEMM1: h = relu(x @ W1 + b1)  M=38400, N=768 -> tiles 150m x 3n = 450 wg (q=56, r=2)
    gemm_t<8, 4, 2, true, true><<<450, 512, LDS1, stream>>>(xw, w1t, b1, (void*)h, 768, 768, 3, 56, 2);
    // GEMM2: out = h @ W2 + b2      M=38400, N=256 -> tiles 150m x 2n = 300 wg (q=37, r=4)
    gemm_t<4, 4, 1, false, false><<<300, 512, LDS2, stream>>>(h, w2t, b2, (void*)out, 768, 256, 2, 37, 4);
}